// Round 5
// baseline (436.742 us; speedup 1.0000x reference)
//
#include <hip/hip_runtime.h>

#define NPTS 12288
#define DIMS 8
#define EPS2 0.25f
#define MINS 5
#define ROWS 2
#define TI   (256 * ROWS)      // 512 rows per adj block
#define SUBT 256               // j-subtile staged in LDS
#define NJB  24
#define JCHUNK (NPTS / NJB)    // 512
#define NIBD (NPTS / TI)       // 24
#define NIB1 (NPTS / 256)      // 48
#define NW   (NPTS / 32)       // 384 words per adjacency row
#define WCH  (JCHUNK / 32)     // 16 words per j-chunk
#define SENT NPTS
#define RMAX 512               // max contracted labels (R~120 measured OK in R3/R4)
#define W    (RMAX / 32)       // 16 words per contracted-bitmap row
#define BIGL 0x3fffffff
#define FT   128               // threads for fill/border kernels

// single distance-computation site (bit-exact vs reference formula)
__device__ __forceinline__ float dist2(const float* xi, const float4& a, const float4& b,
                                       float sqi, float sqj) {
  float dot = 0.f;
  dot = fmaf(xi[0], a.x, dot); dot = fmaf(xi[1], a.y, dot);
  dot = fmaf(xi[2], a.z, dot); dot = fmaf(xi[3], a.w, dot);
  dot = fmaf(xi[4], b.x, dot); dot = fmaf(xi[5], b.y, dot);
  dot = fmaf(xi[6], b.z, dot); dot = fmaf(xi[7], b.w, dot);
  return (sqi + sqj) - 2.0f * dot;
}

// ---------------- kernels ----------------

// the ONLY N^2 distance pass: write eps-adjacency bitmap (every word overwritten)
__global__ __launch_bounds__(256) void k_adj(const float* __restrict__ X,
                                             unsigned int* __restrict__ adj) {
  __shared__ float4 xs[SUBT][2];
  __shared__ float sqs[SUBT];
  int t = threadIdx.x;
  int i0 = blockIdx.x * TI + t, i1 = i0 + 256;
  float xi0[DIMS], xi1[DIMS];
#pragma unroll
  for (int d = 0; d < DIMS; d++) { xi0[d] = X[i0 * DIMS + d]; xi1[d] = X[i1 * DIMS + d]; }
  float sq0 = 0.f, sq1 = 0.f;
#pragma unroll
  for (int d = 0; d < DIMS; d++) { sq0 = fmaf(xi0[d], xi0[d], sq0); sq1 = fmaf(xi1[d], xi1[d], sq1); }
  int j0 = blockIdx.y * JCHUNK;
  unsigned int* r0 = adj + (size_t)i0 * NW + blockIdx.y * WCH;
  unsigned int* r1 = adj + (size_t)i1 * NW + blockIdx.y * WCH;
  for (int js = 0; js < JCHUNK; js += SUBT) {
    __syncthreads();
    {
      int j = j0 + js + t;
      float4 a = ((const float4*)X)[j * 2];
      float4 b = ((const float4*)X)[j * 2 + 1];
      xs[t][0] = a; xs[t][1] = b;
      float s = 0.f;
      s = fmaf(a.x, a.x, s); s = fmaf(a.y, a.y, s); s = fmaf(a.z, a.z, s); s = fmaf(a.w, a.w, s);
      s = fmaf(b.x, b.x, s); s = fmaf(b.y, b.y, s); s = fmaf(b.z, b.z, s); s = fmaf(b.w, b.w, s);
      sqs[t] = s;
    }
    __syncthreads();
    for (int w = 0; w < SUBT / 32; w++) {      // 8 words per subtile
      unsigned int b0 = 0u, b1 = 0u;
#pragma unroll
      for (int bit = 0; bit < 32; bit++) {
        int jj = (w << 5) + bit;
        float4 xa = xs[jj][0], xb = xs[jj][1];
        float sj = sqs[jj];
        b0 |= (dist2(xi0, xa, xb, sq0, sj) <= EPS2) ? (1u << bit) : 0u;
        b1 |= (dist2(xi1, xa, xb, sq1, sj) <= EPS2) ? (1u << bit) : 0u;
      }
      int wi = ((js >> 5) + w);
      r0[wi] = b0; r1[wi] = b1;
    }
  }
}

// density = popcount(row); core bitmap via ballot
__global__ __launch_bounds__(256) void k_post(const unsigned int* __restrict__ adj,
                                              int* __restrict__ density,
                                              unsigned long long* __restrict__ corebm) {
  int i = blockIdx.x * 256 + threadIdx.x;
  const uint4* row = (const uint4*)(adj + (size_t)i * NW);
  int s = 0;
#pragma unroll 8
  for (int q = 0; q < NW / 4; q++) {
    uint4 v = row[q];
    s += __popc(v.x) + __popc(v.y) + __popc(v.z) + __popc(v.w);
  }
  density[i] = s;
  unsigned long long m = __ballot(s >= MINS);
  if ((threadIdx.x & 63) == 0) corebm[i >> 6] = m;
}

// hook[i] = min(i, first set bit of adj[i] & core) -- no atomics
__global__ __launch_bounds__(256) void k_hookbm(const unsigned int* __restrict__ adj,
                                                const unsigned int* __restrict__ cb32,
                                                int* __restrict__ hook) {
  __shared__ unsigned int cb[NW];
  int t = threadIdx.x;
  for (int w = t; w < NW; w += 256) cb[w] = cb32[w];
  __syncthreads();
  int i = blockIdx.x * 256 + t;
  const unsigned int* row = adj + (size_t)i * NW;
  int m = i;
  for (int w = 0; w < NW; w++) {
    unsigned int x = row[w] & cb[w];
    if (x) { m = min(m, (w << 5) + __ffs(x) - 1); break; }
  }
  hook[i] = m;
}

// chase the static hook forest (read-only, strictly decreasing => acyclic)
__global__ __launch_bounds__(256) void k_compress(const int* __restrict__ density,
                                                  const int* __restrict__ hook,
                                                  int* __restrict__ L0) {
  int i = blockIdx.x * blockDim.x + threadIdx.x;
  if (i >= NPTS) return;
  if (density[i] >= MINS) {
    int v = i;
    int h = hook[v];
    while (h != v) { v = h; h = hook[v]; }
    L0[i] = v;
  } else {
    L0[i] = i;
  }
}

// dense root ids + per-point contracted label labL; also zero bcount
__global__ __launch_bounds__(256) void k_rid(const int* __restrict__ density,
                                             const int* __restrict__ L0,
                                             int* __restrict__ rid,
                                             int* __restrict__ Rptr,
                                             int* __restrict__ labL,
                                             int* __restrict__ bcount) {
  __shared__ int wsum[4];
  int t = threadIdx.x;
  int lane = t & 63, wid = t >> 6;
  const int SEG = NPTS / 256;  // 48
  int base = t * SEG;
  int s = 0;
#pragma unroll 4
  for (int k = 0; k < SEG; k++) {
    int i = base + k;
    s += (density[i] >= MINS && L0[i] == i) ? 1 : 0;
  }
  int segsum = s;
#pragma unroll
  for (int off = 1; off < 64; off <<= 1) {
    int n = __shfl_up(s, off, 64);
    if (lane >= off) s += n;
  }
  if (lane == 63) wsum[wid] = s;
  __syncthreads();
  int woff = 0;
  for (int w = 0; w < wid; w++) woff += wsum[w];
  int run = woff + s - segsum;
#pragma unroll 4
  for (int k = 0; k < SEG; k++) {
    int i = base + k;
    rid[i] = run;
    run += (density[i] >= MINS && L0[i] == i) ? 1 : 0;
  }
  if (t == 255) *Rptr = run;
  if (t == 0) *bcount = 0;
  __syncthreads();   // rid[] complete (block-level fence)
#pragma unroll 4
  for (int k = 0; k < SEG; k++) {
    int i = base + k;
    labL[i] = (density[i] >= MINS) ? min(rid[L0[i]], RMAX - 1) : -1;
  }
}

__global__ __launch_bounds__(256) void k_zero(unsigned int* __restrict__ bm) {
  int idx = blockIdx.x * blockDim.x + threadIdx.x;
  if (idx < RMAX * W) bm[idx] = 0u;
}

// crossing-label edges -> contracted adjacency; hot atomics all in LDS
__global__ __launch_bounds__(FT) void k_fillbm(const unsigned int* __restrict__ adj,
                                               const unsigned int* __restrict__ cb32,
                                               const int* __restrict__ labL,
                                               unsigned int* __restrict__ bm) {
  __shared__ unsigned int bmL[RMAX * W];   // 32 KB private bitmap
  __shared__ unsigned int cb[NW];          // 1.5 KB core bitmap
  int t = threadIdx.x;
  for (int q = t; q < RMAX * W; q += FT) bmL[q] = 0u;
  for (int w = t; w < NW; w += FT) cb[w] = cb32[w];
  __syncthreads();
  int i = blockIdx.x * FT + t;
  int a0 = labL[i];
  if (a0 >= 0) {
    const unsigned int* row = adj + (size_t)i * NW;
    for (int w = 0; w < NW; w++) {
      unsigned int x = row[w] & cb[w];
      while (x) {
        int b = __ffs(x) - 1; x &= x - 1;
        int lj = labL[(w << 5) + b];
        if (lj != a0) {
          atomicOr(&bmL[a0 * W + (lj >> 5)], 1u << (lj & 31));
          atomicOr(&bmL[lj * W + (a0 >> 5)], 1u << (a0 & 31));
        }
      }
    }
  }
  __syncthreads();
  for (int q = t; q < RMAX * W; q += FT) {
    unsigned int v = bmL[q];
    if (v) atomicOr(&bm[q], v);
  }
}

// connected components of the contracted graph (single block, LDS) + rank ids
__global__ __launch_bounds__(RMAX) void k_cc(const unsigned int* __restrict__ bm,
                                             const int* __restrict__ Rptr,
                                             int* __restrict__ clab) {
  __shared__ int lbl[RMAX];
  __shared__ int mn[RMAX];
  __shared__ int chg, cmp;
  int a = threadIdx.x;
  int R = *Rptr; if (R > RMAX) R = RMAX;
  lbl[a] = a;
  __syncthreads();
  while (true) {
    int m = lbl[a];
    if (a < R) {
      const unsigned int* row = bm + a * W;
#pragma unroll
      for (int w = 0; w < W; w++) {
        unsigned int bits = row[w];
        while (bits) {
          int b = __ffs(bits) - 1;
          bits &= bits - 1;
          m = min(m, lbl[(w << 5) + b]);
        }
      }
    }
    mn[a] = m;
    if (a == 0) chg = 0;
    __syncthreads();
    int l = lbl[a];
    if (m < l) { atomicMin(&lbl[l], m); atomicMin(&lbl[a], m); chg = 1; }
    __syncthreads();
    while (true) {
      if (a == 0) cmp = 0;
      __syncthreads();
      int nl = lbl[lbl[a]];
      __syncthreads();
      if (nl < lbl[a]) { lbl[a] = nl; cmp = 1; }
      __syncthreads();
      if (!cmp) break;
    }
    if (!chg) break;
    __syncthreads();
  }
  int flag = (a < R && lbl[a] == a) ? 1 : 0;
  mn[a] = flag;
  __syncthreads();
  for (int off = 1; off < RMAX; off <<= 1) {
    int v = mn[a];
    int add = (a >= off) ? mn[a - off] : 0;
    __syncthreads();
    mn[a] = v + add;
    __syncthreads();
  }
  clab[a] = mn[lbl[a]] - 1;
}

// per-point labels; collect border (non-core) points into a compact list
__global__ __launch_bounds__(256) void k_labels(const int* __restrict__ labL,
                                                const int* __restrict__ clab,
                                                int* __restrict__ labArr,
                                                int* __restrict__ blist,
                                                int* __restrict__ bcount,
                                                float* __restrict__ out) {
  int i = blockIdx.x * blockDim.x + threadIdx.x;
  if (i >= NPTS) return;
  int a = labL[i];
  if (a >= 0) {
    int lab = clab[a];
    labArr[i] = lab;
    out[i] = (float)lab;
  } else {
    labArr[i] = BIGL;
    out[i] = -1.0f;
    int pos = atomicAdd(bcount, 1);
    blist[pos] = i;
  }
}

// one block per border point: min cluster id over core neighbors (bitmap scan)
__global__ __launch_bounds__(FT) void k_border(const unsigned int* __restrict__ adj,
                                               const unsigned int* __restrict__ cb32,
                                               const int* __restrict__ labArr,
                                               const int* __restrict__ blist,
                                               const int* __restrict__ bcount,
                                               float* __restrict__ out) {
  __shared__ unsigned int cb[NW];
  __shared__ int wm[FT / 64];
  int t = threadIdx.x;
  for (int w = t; w < NW; w += FT) cb[w] = cb32[w];
  __syncthreads();
  int count = *bcount;
  for (int k = blockIdx.x; k < count; k += gridDim.x) {
    int p = blist[k];
    const unsigned int* row = adj + (size_t)p * NW;
    int m = BIGL;
    for (int w = t; w < NW; w += FT) {
      unsigned int x = row[w] & cb[w];
      while (x) {
        int b = __ffs(x) - 1; x &= x - 1;
        m = min(m, labArr[(w << 5) + b]);
      }
    }
#pragma unroll
    for (int off = 32; off >= 1; off >>= 1) m = min(m, __shfl_xor(m, off, 64));
    if ((t & 63) == 0) wm[t >> 6] = m;
    __syncthreads();
    if (t == 0) {
      int mm = min(wm[0], wm[1]);
      out[p] = (mm < BIGL) ? (float)mm : -1.0f;
    }
    __syncthreads();
  }
}

// ---------------- launch ----------------

extern "C" void kernel_launch(void* const* d_in, const int* in_sizes, int n_in,
                              void* d_out, int out_size, void* d_ws, size_t ws_size,
                              hipStream_t stream) {
  const float* X = (const float*)d_in[0];
  float* out = (float*)d_out;

  char* ws = (char*)d_ws;
  unsigned int* adj = (unsigned int*)ws;                     // 18,874,368 B
  size_t off = (size_t)NPTS * NW * 4;
  int* density = (int*)(ws + off);           off += 4 * NPTS;
  int* hook    = (int*)(ws + off);           off += 4 * NPTS;
  int* L0      = (int*)(ws + off);           off += 4 * NPTS;   // -> labArr
  int* labL    = (int*)(ws + off);           off += 4 * NPTS;
  int* blist   = (int*)(ws + off);           off += 4 * NPTS;
  int* rid     = (int*)(ws + off);           off += 4 * NPTS;
  unsigned long long* corebm = (unsigned long long*)(ws + off); off += 2048;
  unsigned int* bm  = (unsigned int*)(ws + off); off += 4 * RMAX * W;
  int* clab    = (int*)(ws + off);           off += 4 * RMAX;
  int* Rptr    = (int*)(ws + off);
  int* bcount  = Rptr + 1;
  int* labArr  = L0;   // L0 dead after k_rid

  dim3 gridA(NIBD, NJB);

  k_adj<<<gridA, 256, 0, stream>>>(X, adj);
  k_post<<<NIB1, 256, 0, stream>>>(adj, density, corebm);
  k_hookbm<<<NIB1, 256, 0, stream>>>(adj, (const unsigned int*)corebm, hook);
  k_compress<<<NIB1, 256, 0, stream>>>(density, hook, L0);
  k_rid<<<1, 256, 0, stream>>>(density, L0, rid, Rptr, labL, bcount);
  k_zero<<<(RMAX * W + 255) / 256, 256, 0, stream>>>(bm);
  k_fillbm<<<NPTS / FT, FT, 0, stream>>>(adj, (const unsigned int*)corebm, labL, bm);
  k_cc<<<1, RMAX, 0, stream>>>(bm, Rptr, clab);
  k_labels<<<NIB1, 256, 0, stream>>>(labL, clab, labArr, blist, bcount, out);
  k_border<<<256, FT, 0, stream>>>(adj, (const unsigned int*)corebm, labArr, blist, bcount, out);
}

// Round 6
// 315.104 us; speedup vs baseline: 1.3860x; 1.3860x over previous
//
#include <hip/hip_runtime.h>

#define NPTS 12288
#define DIMS 8
#define EPS2 0.25f
#define MINS 5
#define ROWS 2
#define TI   (256 * ROWS)      // 512 rows per adj block
#define SUBT 256               // j-subtile staged in LDS
#define NJB  24
#define JCHUNK (NPTS / NJB)    // 512
#define NIBD (NPTS / TI)       // 24
#define NIB1 (NPTS / 256)      // 48
#define NW   (NPTS / 32)       // 384 words per adjacency row
#define WCH  (JCHUNK / 32)     // 16 words per j-chunk
#define SENT NPTS
#define RMAX 512               // max contracted labels (R~120 measured OK)
#define W    (RMAX / 32)       // 16 words per contracted-bitmap row
#define BIGL 0x3fffffff
#define FT   128               // threads for border kernel
#define FB   256               // threads for fillbm
#define FBGRID 256             // blocks for fillbm -> 1024 waves

// single distance-computation site (bit-exact vs reference formula)
__device__ __forceinline__ float dist2(const float* xi, const float4& a, const float4& b,
                                       float sqi, float sqj) {
  float dot = 0.f;
  dot = fmaf(xi[0], a.x, dot); dot = fmaf(xi[1], a.y, dot);
  dot = fmaf(xi[2], a.z, dot); dot = fmaf(xi[3], a.w, dot);
  dot = fmaf(xi[4], b.x, dot); dot = fmaf(xi[5], b.y, dot);
  dot = fmaf(xi[6], b.z, dot); dot = fmaf(xi[7], b.w, dot);
  return (sqi + sqj) - 2.0f * dot;
}

// ---------------- kernels ----------------

// the ONLY N^2 distance pass: write eps-adjacency bitmap (every word overwritten)
__global__ __launch_bounds__(256) void k_adj(const float* __restrict__ X,
                                             unsigned int* __restrict__ adj) {
  __shared__ float4 xs[SUBT][2];
  __shared__ float sqs[SUBT];
  int t = threadIdx.x;
  int i0 = blockIdx.x * TI + t, i1 = i0 + 256;
  float xi0[DIMS], xi1[DIMS];
#pragma unroll
  for (int d = 0; d < DIMS; d++) { xi0[d] = X[i0 * DIMS + d]; xi1[d] = X[i1 * DIMS + d]; }
  float sq0 = 0.f, sq1 = 0.f;
#pragma unroll
  for (int d = 0; d < DIMS; d++) { sq0 = fmaf(xi0[d], xi0[d], sq0); sq1 = fmaf(xi1[d], xi1[d], sq1); }
  int j0 = blockIdx.y * JCHUNK;
  unsigned int* r0 = adj + (size_t)i0 * NW + blockIdx.y * WCH;
  unsigned int* r1 = adj + (size_t)i1 * NW + blockIdx.y * WCH;
  for (int js = 0; js < JCHUNK; js += SUBT) {
    __syncthreads();
    {
      int j = j0 + js + t;
      float4 a = ((const float4*)X)[j * 2];
      float4 b = ((const float4*)X)[j * 2 + 1];
      xs[t][0] = a; xs[t][1] = b;
      float s = 0.f;
      s = fmaf(a.x, a.x, s); s = fmaf(a.y, a.y, s); s = fmaf(a.z, a.z, s); s = fmaf(a.w, a.w, s);
      s = fmaf(b.x, b.x, s); s = fmaf(b.y, b.y, s); s = fmaf(b.z, b.z, s); s = fmaf(b.w, b.w, s);
      sqs[t] = s;
    }
    __syncthreads();
    for (int w = 0; w < SUBT / 32; w++) {      // 8 words per subtile
      unsigned int b0 = 0u, b1 = 0u;
#pragma unroll
      for (int bit = 0; bit < 32; bit++) {
        int jj = (w << 5) + bit;
        float4 xa = xs[jj][0], xb = xs[jj][1];
        float sj = sqs[jj];
        b0 |= (dist2(xi0, xa, xb, sq0, sj) <= EPS2) ? (1u << bit) : 0u;
        b1 |= (dist2(xi1, xa, xb, sq1, sj) <= EPS2) ? (1u << bit) : 0u;
      }
      int wi = ((js >> 5) + w);
      r0[wi] = b0; r1[wi] = b1;
    }
  }
}

// density = popcount(row); core bitmap via ballot
__global__ __launch_bounds__(256) void k_post(const unsigned int* __restrict__ adj,
                                              int* __restrict__ density,
                                              unsigned long long* __restrict__ corebm) {
  int i = blockIdx.x * 256 + threadIdx.x;
  const uint4* row = (const uint4*)(adj + (size_t)i * NW);
  int s = 0;
#pragma unroll 8
  for (int q = 0; q < NW / 4; q++) {
    uint4 v = row[q];
    s += __popc(v.x) + __popc(v.y) + __popc(v.z) + __popc(v.w);
  }
  density[i] = s;
  unsigned long long m = __ballot(s >= MINS);
  if ((threadIdx.x & 63) == 0) corebm[i >> 6] = m;
}

// hook[i] = min(i, first set bit of adj[i] & core) -- no atomics
__global__ __launch_bounds__(256) void k_hookbm(const unsigned int* __restrict__ adj,
                                                const unsigned int* __restrict__ cb32,
                                                int* __restrict__ hook) {
  __shared__ unsigned int cb[NW];
  int t = threadIdx.x;
  for (int w = t; w < NW; w += 256) cb[w] = cb32[w];
  __syncthreads();
  int i = blockIdx.x * 256 + t;
  const unsigned int* row = adj + (size_t)i * NW;
  int m = i;
  for (int w = 0; w < NW; w++) {
    unsigned int x = row[w] & cb[w];
    if (x) { m = min(m, (w << 5) + __ffs(x) - 1); break; }
  }
  hook[i] = m;
}

// chase the static hook forest (read-only, strictly decreasing => acyclic)
__global__ __launch_bounds__(256) void k_compress(const int* __restrict__ density,
                                                  const int* __restrict__ hook,
                                                  int* __restrict__ L0) {
  int i = blockIdx.x * blockDim.x + threadIdx.x;
  if (i >= NPTS) return;
  if (density[i] >= MINS) {
    int v = i;
    int h = hook[v];
    while (h != v) { v = h; h = hook[v]; }
    L0[i] = v;
  } else {
    L0[i] = i;
  }
}

// dense root ids + per-point contracted label labL; also zero bcount
__global__ __launch_bounds__(256) void k_rid(const int* __restrict__ density,
                                             const int* __restrict__ L0,
                                             int* __restrict__ rid,
                                             int* __restrict__ Rptr,
                                             int* __restrict__ labL,
                                             int* __restrict__ bcount) {
  __shared__ int wsum[4];
  int t = threadIdx.x;
  int lane = t & 63, wid = t >> 6;
  const int SEG = NPTS / 256;  // 48
  int base = t * SEG;
  int s = 0;
#pragma unroll 4
  for (int k = 0; k < SEG; k++) {
    int i = base + k;
    s += (density[i] >= MINS && L0[i] == i) ? 1 : 0;
  }
  int segsum = s;
#pragma unroll
  for (int off = 1; off < 64; off <<= 1) {
    int n = __shfl_up(s, off, 64);
    if (lane >= off) s += n;
  }
  if (lane == 63) wsum[wid] = s;
  __syncthreads();
  int woff = 0;
  for (int w = 0; w < wid; w++) woff += wsum[w];
  int run = woff + s - segsum;
#pragma unroll 4
  for (int k = 0; k < SEG; k++) {
    int i = base + k;
    rid[i] = run;
    run += (density[i] >= MINS && L0[i] == i) ? 1 : 0;
  }
  if (t == 255) *Rptr = run;
  if (t == 0) *bcount = 0;
  __syncthreads();   // rid[] complete (block-level fence)
#pragma unroll 4
  for (int k = 0; k < SEG; k++) {
    int i = base + k;
    labL[i] = (density[i] >= MINS) ? min(rid[L0[i]], RMAX - 1) : -1;
  }
}

__global__ __launch_bounds__(256) void k_zero(unsigned int* __restrict__ bm) {
  int idx = blockIdx.x * blockDim.x + threadIdx.x;
  if (idx < RMAX * W) bm[idx] = 0u;
}

// crossing-label edges -> contracted adjacency.
// Wave-per-row: 64 lanes stride the row's 384 words (coalesced); labels read
// from LDS (16-bit); all hot atomics in LDS; one batched merge at block end.
__global__ __launch_bounds__(FB) void k_fillbm(const unsigned int* __restrict__ adj,
                                               const unsigned int* __restrict__ cb32,
                                               const int* __restrict__ labL,
                                               unsigned int* __restrict__ bm) {
  __shared__ unsigned int bmL[RMAX * W];       // 32 KB private bitmap
  __shared__ unsigned short labS[NPTS];        // 24 KB labels (+1, 0 = non-core)
  __shared__ unsigned int cb[NW];              // 1.5 KB core bitmap
  int t = threadIdx.x;
  for (int q = t; q < RMAX * W; q += FB) bmL[q] = 0u;
  for (int q = t; q < NPTS; q += FB) labS[q] = (unsigned short)(labL[q] + 1);
  for (int w = t; w < NW; w += FB) cb[w] = cb32[w];
  __syncthreads();
  int lane = t & 63, wv = t >> 6;              // 4 waves per block
  int gw = blockIdx.x * 4 + wv;                // global wave id 0..1023
  for (int i = gw; i < NPTS; i += 4 * FBGRID) {
    int a0 = (int)labS[i] - 1;
    if (a0 < 0) continue;                      // wave-uniform
    const unsigned int* row = adj + (size_t)i * NW;
    for (int w = lane; w < NW; w += 64) {
      unsigned int x = row[w] & cb[w];
      while (x) {
        int b = __ffs(x) - 1; x &= x - 1;
        int lj = (int)labS[(w << 5) + b] - 1;
        if (lj != a0) {
          atomicOr(&bmL[a0 * W + (lj >> 5)], 1u << (lj & 31));
          atomicOr(&bmL[lj * W + (a0 >> 5)], 1u << (a0 & 31));
        }
      }
    }
  }
  __syncthreads();
  for (int q = t; q < RMAX * W; q += FB) {
    unsigned int v = bmL[q];
    if (v) atomicOr(&bm[q], v);
  }
}

// connected components of the contracted graph (single block, LDS) + rank ids
__global__ __launch_bounds__(RMAX) void k_cc(const unsigned int* __restrict__ bm,
                                             const int* __restrict__ Rptr,
                                             int* __restrict__ clab) {
  __shared__ int lbl[RMAX];
  __shared__ int mn[RMAX];
  __shared__ int chg, cmp;
  int a = threadIdx.x;
  int R = *Rptr; if (R > RMAX) R = RMAX;
  lbl[a] = a;
  __syncthreads();
  while (true) {
    int m = lbl[a];
    if (a < R) {
      const unsigned int* row = bm + a * W;
#pragma unroll
      for (int w = 0; w < W; w++) {
        unsigned int bits = row[w];
        while (bits) {
          int b = __ffs(bits) - 1;
          bits &= bits - 1;
          m = min(m, lbl[(w << 5) + b]);
        }
      }
    }
    mn[a] = m;
    if (a == 0) chg = 0;
    __syncthreads();
    int l = lbl[a];
    if (m < l) { atomicMin(&lbl[l], m); atomicMin(&lbl[a], m); chg = 1; }
    __syncthreads();
    while (true) {
      if (a == 0) cmp = 0;
      __syncthreads();
      int nl = lbl[lbl[a]];
      __syncthreads();
      if (nl < lbl[a]) { lbl[a] = nl; cmp = 1; }
      __syncthreads();
      if (!cmp) break;
    }
    if (!chg) break;
    __syncthreads();
  }
  int flag = (a < R && lbl[a] == a) ? 1 : 0;
  mn[a] = flag;
  __syncthreads();
  for (int off = 1; off < RMAX; off <<= 1) {
    int v = mn[a];
    int add = (a >= off) ? mn[a - off] : 0;
    __syncthreads();
    mn[a] = v + add;
    __syncthreads();
  }
  clab[a] = mn[lbl[a]] - 1;
}

// per-point labels; collect border (non-core) points into a compact list
__global__ __launch_bounds__(256) void k_labels(const int* __restrict__ labL,
                                                const int* __restrict__ clab,
                                                int* __restrict__ labArr,
                                                int* __restrict__ blist,
                                                int* __restrict__ bcount,
                                                float* __restrict__ out) {
  int i = blockIdx.x * blockDim.x + threadIdx.x;
  if (i >= NPTS) return;
  int a = labL[i];
  if (a >= 0) {
    int lab = clab[a];
    labArr[i] = lab;
    out[i] = (float)lab;
  } else {
    labArr[i] = BIGL;
    out[i] = -1.0f;
    int pos = atomicAdd(bcount, 1);
    blist[pos] = i;
  }
}

// one block per border point: min cluster id over core neighbors (bitmap scan)
__global__ __launch_bounds__(FT) void k_border(const unsigned int* __restrict__ adj,
                                               const unsigned int* __restrict__ cb32,
                                               const int* __restrict__ labArr,
                                               const int* __restrict__ blist,
                                               const int* __restrict__ bcount,
                                               float* __restrict__ out) {
  __shared__ unsigned int cb[NW];
  __shared__ int wm[FT / 64];
  int t = threadIdx.x;
  for (int w = t; w < NW; w += FT) cb[w] = cb32[w];
  __syncthreads();
  int count = *bcount;
  for (int k = blockIdx.x; k < count; k += gridDim.x) {
    int p = blist[k];
    const unsigned int* row = adj + (size_t)p * NW;
    int m = BIGL;
    for (int w = t; w < NW; w += FT) {
      unsigned int x = row[w] & cb[w];
      while (x) {
        int b = __ffs(x) - 1; x &= x - 1;
        m = min(m, labArr[(w << 5) + b]);
      }
    }
#pragma unroll
    for (int off = 32; off >= 1; off >>= 1) m = min(m, __shfl_xor(m, off, 64));
    if ((t & 63) == 0) wm[t >> 6] = m;
    __syncthreads();
    if (t == 0) {
      int mm = min(wm[0], wm[1]);
      out[p] = (mm < BIGL) ? (float)mm : -1.0f;
    }
    __syncthreads();
  }
}

// ---------------- launch ----------------

extern "C" void kernel_launch(void* const* d_in, const int* in_sizes, int n_in,
                              void* d_out, int out_size, void* d_ws, size_t ws_size,
                              hipStream_t stream) {
  const float* X = (const float*)d_in[0];
  float* out = (float*)d_out;

  char* ws = (char*)d_ws;
  unsigned int* adj = (unsigned int*)ws;                     // 18,874,368 B
  size_t off = (size_t)NPTS * NW * 4;
  int* density = (int*)(ws + off);           off += 4 * NPTS;
  int* hook    = (int*)(ws + off);           off += 4 * NPTS;
  int* L0      = (int*)(ws + off);           off += 4 * NPTS;   // -> labArr
  int* labL    = (int*)(ws + off);           off += 4 * NPTS;
  int* blist   = (int*)(ws + off);           off += 4 * NPTS;
  int* rid     = (int*)(ws + off);           off += 4 * NPTS;
  unsigned long long* corebm = (unsigned long long*)(ws + off); off += 2048;
  unsigned int* bm  = (unsigned int*)(ws + off); off += 4 * RMAX * W;
  int* clab    = (int*)(ws + off);           off += 4 * RMAX;
  int* Rptr    = (int*)(ws + off);
  int* bcount  = Rptr + 1;
  int* labArr  = L0;   // L0 dead after k_rid

  dim3 gridA(NIBD, NJB);

  k_adj<<<gridA, 256, 0, stream>>>(X, adj);
  k_post<<<NIB1, 256, 0, stream>>>(adj, density, corebm);
  k_hookbm<<<NIB1, 256, 0, stream>>>(adj, (const unsigned int*)corebm, hook);
  k_compress<<<NIB1, 256, 0, stream>>>(density, hook, L0);
  k_rid<<<1, 256, 0, stream>>>(density, L0, rid, Rptr, labL, bcount);
  k_zero<<<(RMAX * W + 255) / 256, 256, 0, stream>>>(bm);
  k_fillbm<<<FBGRID, FB, 0, stream>>>(adj, (const unsigned int*)corebm, labL, bm);
  k_cc<<<1, RMAX, 0, stream>>>(bm, Rptr, clab);
  k_labels<<<NIB1, 256, 0, stream>>>(labL, clab, labArr, blist, bcount, out);
  k_border<<<256, FT, 0, stream>>>(adj, (const unsigned int*)corebm, labArr, blist, bcount, out);
}

// Round 7
// 260.227 us; speedup vs baseline: 1.6783x; 1.2109x over previous
//
#include <hip/hip_runtime.h>

#define NPTS 12288
#define DIMS 8
#define EPS2 0.25f
#define MINS 5
#define ROWS 2
#define TI   (256 * ROWS)      // 512 rows per adj block
#define SUBT 256               // j-subtile staged in LDS
#define NJB  24
#define JCHUNK (NPTS / NJB)    // 512
#define NIBD (NPTS / TI)       // 24
#define NIB1 (NPTS / 256)      // 48
#define NW   (NPTS / 32)       // 384 words per adjacency row
#define WCH  (JCHUNK / 32)     // 16 words per j-chunk
#define SENT NPTS
#define RMAX 512               // max contracted labels (R~120 measured OK)
#define W    (RMAX / 32)       // 16 words per contracted-bitmap row
#define BIGL 0x3fffffff
#define FT   128               // threads for border kernel
#define FB   256               // threads for fillbm
#define FBGRID 256             // blocks for fillbm -> 1024 waves

// single distance-computation site (bit-exact vs reference formula)
__device__ __forceinline__ float dist2(const float* xi, const float4& a, const float4& b,
                                       float sqi, float sqj) {
  float dot = 0.f;
  dot = fmaf(xi[0], a.x, dot); dot = fmaf(xi[1], a.y, dot);
  dot = fmaf(xi[2], a.z, dot); dot = fmaf(xi[3], a.w, dot);
  dot = fmaf(xi[4], b.x, dot); dot = fmaf(xi[5], b.y, dot);
  dot = fmaf(xi[6], b.z, dot); dot = fmaf(xi[7], b.w, dot);
  return (sqi + sqj) - 2.0f * dot;
}

// ---------------- kernels ----------------

// the ONLY N^2 distance pass: write eps-adjacency bitmap (every word overwritten)
__global__ __launch_bounds__(256) void k_adj(const float* __restrict__ X,
                                             unsigned int* __restrict__ adj) {
  __shared__ float4 xs[SUBT][2];
  __shared__ float sqs[SUBT];
  int t = threadIdx.x;
  int i0 = blockIdx.x * TI + t, i1 = i0 + 256;
  float xi0[DIMS], xi1[DIMS];
#pragma unroll
  for (int d = 0; d < DIMS; d++) { xi0[d] = X[i0 * DIMS + d]; xi1[d] = X[i1 * DIMS + d]; }
  float sq0 = 0.f, sq1 = 0.f;
#pragma unroll
  for (int d = 0; d < DIMS; d++) { sq0 = fmaf(xi0[d], xi0[d], sq0); sq1 = fmaf(xi1[d], xi1[d], sq1); }
  int j0 = blockIdx.y * JCHUNK;
  unsigned int* r0 = adj + (size_t)i0 * NW + blockIdx.y * WCH;
  unsigned int* r1 = adj + (size_t)i1 * NW + blockIdx.y * WCH;
  for (int js = 0; js < JCHUNK; js += SUBT) {
    __syncthreads();
    {
      int j = j0 + js + t;
      float4 a = ((const float4*)X)[j * 2];
      float4 b = ((const float4*)X)[j * 2 + 1];
      xs[t][0] = a; xs[t][1] = b;
      float s = 0.f;
      s = fmaf(a.x, a.x, s); s = fmaf(a.y, a.y, s); s = fmaf(a.z, a.z, s); s = fmaf(a.w, a.w, s);
      s = fmaf(b.x, b.x, s); s = fmaf(b.y, b.y, s); s = fmaf(b.z, b.z, s); s = fmaf(b.w, b.w, s);
      sqs[t] = s;
    }
    __syncthreads();
    for (int w = 0; w < SUBT / 32; w++) {      // 8 words per subtile
      unsigned int b0 = 0u, b1 = 0u;
#pragma unroll
      for (int bit = 0; bit < 32; bit++) {
        int jj = (w << 5) + bit;
        float4 xa = xs[jj][0], xb = xs[jj][1];
        float sj = sqs[jj];
        b0 |= (dist2(xi0, xa, xb, sq0, sj) <= EPS2) ? (1u << bit) : 0u;
        b1 |= (dist2(xi1, xa, xb, sq1, sj) <= EPS2) ? (1u << bit) : 0u;
      }
      int wi = ((js >> 5) + w);
      r0[wi] = b0; r1[wi] = b1;
    }
  }
}

// density = popcount(row); core bitmap via ballot
__global__ __launch_bounds__(256) void k_post(const unsigned int* __restrict__ adj,
                                              int* __restrict__ density,
                                              unsigned long long* __restrict__ corebm) {
  int i = blockIdx.x * 256 + threadIdx.x;
  const uint4* row = (const uint4*)(adj + (size_t)i * NW);
  int s = 0;
#pragma unroll 8
  for (int q = 0; q < NW / 4; q++) {
    uint4 v = row[q];
    s += __popc(v.x) + __popc(v.y) + __popc(v.z) + __popc(v.w);
  }
  density[i] = s;
  unsigned long long m = __ballot(s >= MINS);
  if ((threadIdx.x & 63) == 0) corebm[i >> 6] = m;
}

// hook[i] = min(i, first set bit of adj[i] & core) -- no atomics
__global__ __launch_bounds__(256) void k_hookbm(const unsigned int* __restrict__ adj,
                                                const unsigned int* __restrict__ cb32,
                                                int* __restrict__ hook) {
  __shared__ unsigned int cb[NW];
  int t = threadIdx.x;
  for (int w = t; w < NW; w += 256) cb[w] = cb32[w];
  __syncthreads();
  int i = blockIdx.x * 256 + t;
  const unsigned int* row = adj + (size_t)i * NW;
  int m = i;
  for (int w = 0; w < NW; w++) {
    unsigned int x = row[w] & cb[w];
    if (x) { m = min(m, (w << 5) + __ffs(x) - 1); break; }
  }
  hook[i] = m;
}

// chase the static hook forest (read-only, strictly decreasing => acyclic)
__global__ __launch_bounds__(256) void k_compress(const int* __restrict__ density,
                                                  const int* __restrict__ hook,
                                                  int* __restrict__ L0) {
  int i = blockIdx.x * blockDim.x + threadIdx.x;
  if (i >= NPTS) return;
  if (density[i] >= MINS) {
    int v = i;
    int h = hook[v];
    while (h != v) { v = h; h = hook[v]; }
    L0[i] = v;
  } else {
    L0[i] = i;
  }
}

// root ranks in LDS + labL in one pass; 1024 threads for latency overlap.
// labL[i] = dense id of i's forest root (clamped), or -1 for non-core.
__global__ __launch_bounds__(1024) void k_rid(const int* __restrict__ density,
                                              const int* __restrict__ L0,
                                              int* __restrict__ Rptr,
                                              int* __restrict__ labL,
                                              int* __restrict__ bcount) {
  __shared__ unsigned short ridS[NPTS];   // 24 KB: rank of each root index
  __shared__ int wsum[16];
  int t = threadIdx.x;
  int lane = t & 63, wid = t >> 6;
  const int SEG = NPTS / 1024;  // 12
  int base = t * SEG;
  int flags = 0;                // bit k = is_root(base+k)
  int s = 0;
#pragma unroll
  for (int k = 0; k < SEG; k++) {
    int i = base + k;
    int f = (density[i] >= MINS && L0[i] == i) ? 1 : 0;
    flags |= f << k;
    s += f;
  }
  int segsum = s;
#pragma unroll
  for (int off = 1; off < 64; off <<= 1) {
    int n = __shfl_up(s, off, 64);
    if (lane >= off) s += n;
  }
  if (lane == 63) wsum[wid] = s;
  __syncthreads();
  int woff = 0;
  for (int w = 0; w < wid; w++) woff += wsum[w];
  int run = woff + s - segsum;  // exclusive prefix before my segment
#pragma unroll
  for (int k = 0; k < SEG; k++) {
    ridS[base + k] = (unsigned short)run;
    run += (flags >> k) & 1;
  }
  if (t == 1023) *Rptr = run;
  if (t == 0) *bcount = 0;
  __syncthreads();   // ridS complete
#pragma unroll
  for (int k = 0; k < SEG; k++) {
    int i = base + k;
    labL[i] = (density[i] >= MINS) ? min((int)ridS[L0[i]], RMAX - 1) : -1;
  }
}

__global__ __launch_bounds__(256) void k_zero(unsigned int* __restrict__ bm) {
  int idx = blockIdx.x * blockDim.x + threadIdx.x;
  if (idx < RMAX * W) bm[idx] = 0u;
}

// crossing-label edges -> contracted adjacency.
// Wave-per-row: 64 lanes stride the row's 384 words (coalesced); labels read
// from LDS (16-bit); all hot atomics in LDS; one batched merge at block end.
__global__ __launch_bounds__(FB) void k_fillbm(const unsigned int* __restrict__ adj,
                                               const unsigned int* __restrict__ cb32,
                                               const int* __restrict__ labL,
                                               unsigned int* __restrict__ bm) {
  __shared__ unsigned int bmL[RMAX * W];       // 32 KB private bitmap
  __shared__ unsigned short labS[NPTS];        // 24 KB labels (+1, 0 = non-core)
  __shared__ unsigned int cb[NW];              // 1.5 KB core bitmap
  int t = threadIdx.x;
  for (int q = t; q < RMAX * W; q += FB) bmL[q] = 0u;
  for (int q = t; q < NPTS; q += FB) labS[q] = (unsigned short)(labL[q] + 1);
  for (int w = t; w < NW; w += FB) cb[w] = cb32[w];
  __syncthreads();
  int lane = t & 63, wv = t >> 6;              // 4 waves per block
  int gw = blockIdx.x * 4 + wv;                // global wave id 0..1023
  for (int i = gw; i < NPTS; i += 4 * FBGRID) {
    int a0 = (int)labS[i] - 1;
    if (a0 < 0) continue;                      // wave-uniform
    const unsigned int* row = adj + (size_t)i * NW;
    for (int w = lane; w < NW; w += 64) {
      unsigned int x = row[w] & cb[w];
      while (x) {
        int b = __ffs(x) - 1; x &= x - 1;
        int lj = (int)labS[(w << 5) + b] - 1;
        if (lj != a0) {
          atomicOr(&bmL[a0 * W + (lj >> 5)], 1u << (lj & 31));
          atomicOr(&bmL[lj * W + (a0 >> 5)], 1u << (a0 & 31));
        }
      }
    }
  }
  __syncthreads();
  for (int q = t; q < RMAX * W; q += FB) {
    unsigned int v = bmL[q];
    if (v) atomicOr(&bm[q], v);
  }
}

// connected components of the contracted graph (single block, LDS) + rank ids
__global__ __launch_bounds__(RMAX) void k_cc(const unsigned int* __restrict__ bm,
                                             const int* __restrict__ Rptr,
                                             int* __restrict__ clab) {
  __shared__ int lbl[RMAX];
  __shared__ int mn[RMAX];
  __shared__ int chg, cmp;
  int a = threadIdx.x;
  int R = *Rptr; if (R > RMAX) R = RMAX;
  lbl[a] = a;
  __syncthreads();
  while (true) {
    int m = lbl[a];
    if (a < R) {
      const unsigned int* row = bm + a * W;
#pragma unroll
      for (int w = 0; w < W; w++) {
        unsigned int bits = row[w];
        while (bits) {
          int b = __ffs(bits) - 1;
          bits &= bits - 1;
          m = min(m, lbl[(w << 5) + b]);
        }
      }
    }
    mn[a] = m;
    if (a == 0) chg = 0;
    __syncthreads();
    int l = lbl[a];
    if (m < l) { atomicMin(&lbl[l], m); atomicMin(&lbl[a], m); chg = 1; }
    __syncthreads();
    while (true) {
      if (a == 0) cmp = 0;
      __syncthreads();
      int nl = lbl[lbl[a]];
      __syncthreads();
      if (nl < lbl[a]) { lbl[a] = nl; cmp = 1; }
      __syncthreads();
      if (!cmp) break;
    }
    if (!chg) break;
    __syncthreads();
  }
  int flag = (a < R && lbl[a] == a) ? 1 : 0;
  mn[a] = flag;
  __syncthreads();
  for (int off = 1; off < RMAX; off <<= 1) {
    int v = mn[a];
    int add = (a >= off) ? mn[a - off] : 0;
    __syncthreads();
    mn[a] = v + add;
    __syncthreads();
  }
  clab[a] = mn[lbl[a]] - 1;
}

// per-point labels; collect border (non-core) points into a compact list
__global__ __launch_bounds__(256) void k_labels(const int* __restrict__ labL,
                                                const int* __restrict__ clab,
                                                int* __restrict__ labArr,
                                                int* __restrict__ blist,
                                                int* __restrict__ bcount,
                                                float* __restrict__ out) {
  int i = blockIdx.x * blockDim.x + threadIdx.x;
  if (i >= NPTS) return;
  int a = labL[i];
  if (a >= 0) {
    int lab = clab[a];
    labArr[i] = lab;
    out[i] = (float)lab;
  } else {
    labArr[i] = BIGL;
    out[i] = -1.0f;
    int pos = atomicAdd(bcount, 1);
    blist[pos] = i;
  }
}

// one block per border point: min cluster id over core neighbors (bitmap scan)
__global__ __launch_bounds__(FT) void k_border(const unsigned int* __restrict__ adj,
                                               const unsigned int* __restrict__ cb32,
                                               const int* __restrict__ labArr,
                                               const int* __restrict__ blist,
                                               const int* __restrict__ bcount,
                                               float* __restrict__ out) {
  __shared__ unsigned int cb[NW];
  __shared__ int wm[FT / 64];
  int t = threadIdx.x;
  for (int w = t; w < NW; w += FT) cb[w] = cb32[w];
  __syncthreads();
  int count = *bcount;
  for (int k = blockIdx.x; k < count; k += gridDim.x) {
    int p = blist[k];
    const unsigned int* row = adj + (size_t)p * NW;
    int m = BIGL;
    for (int w = t; w < NW; w += FT) {
      unsigned int x = row[w] & cb[w];
      while (x) {
        int b = __ffs(x) - 1; x &= x - 1;
        m = min(m, labArr[(w << 5) + b]);
      }
    }
#pragma unroll
    for (int off = 32; off >= 1; off >>= 1) m = min(m, __shfl_xor(m, off, 64));
    if ((t & 63) == 0) wm[t >> 6] = m;
    __syncthreads();
    if (t == 0) {
      int mm = min(wm[0], wm[1]);
      out[p] = (mm < BIGL) ? (float)mm : -1.0f;
    }
    __syncthreads();
  }
}

// ---------------- launch ----------------

extern "C" void kernel_launch(void* const* d_in, const int* in_sizes, int n_in,
                              void* d_out, int out_size, void* d_ws, size_t ws_size,
                              hipStream_t stream) {
  const float* X = (const float*)d_in[0];
  float* out = (float*)d_out;

  char* ws = (char*)d_ws;
  unsigned int* adj = (unsigned int*)ws;                     // 18,874,368 B
  size_t off = (size_t)NPTS * NW * 4;
  int* density = (int*)(ws + off);           off += 4 * NPTS;
  int* hook    = (int*)(ws + off);           off += 4 * NPTS;
  int* L0      = (int*)(ws + off);           off += 4 * NPTS;   // -> labArr
  int* labL    = (int*)(ws + off);           off += 4 * NPTS;
  int* blist   = (int*)(ws + off);           off += 4 * NPTS;
  unsigned long long* corebm = (unsigned long long*)(ws + off); off += 2048;
  unsigned int* bm  = (unsigned int*)(ws + off); off += 4 * RMAX * W;
  int* clab    = (int*)(ws + off);           off += 4 * RMAX;
  int* Rptr    = (int*)(ws + off);
  int* bcount  = Rptr + 1;
  int* labArr  = L0;   // L0 dead after k_rid

  dim3 gridA(NIBD, NJB);

  k_adj<<<gridA, 256, 0, stream>>>(X, adj);
  k_post<<<NIB1, 256, 0, stream>>>(adj, density, corebm);
  k_hookbm<<<NIB1, 256, 0, stream>>>(adj, (const unsigned int*)corebm, hook);
  k_compress<<<NIB1, 256, 0, stream>>>(density, hook, L0);
  k_rid<<<1, 1024, 0, stream>>>(density, L0, Rptr, labL, bcount);
  k_zero<<<(RMAX * W + 255) / 256, 256, 0, stream>>>(bm);
  k_fillbm<<<FBGRID, FB, 0, stream>>>(adj, (const unsigned int*)corebm, labL, bm);
  k_cc<<<1, RMAX, 0, stream>>>(bm, Rptr, clab);
  k_labels<<<NIB1, 256, 0, stream>>>(labL, clab, labArr, blist, bcount, out);
  k_border<<<256, FT, 0, stream>>>(adj, (const unsigned int*)corebm, labArr, blist, bcount, out);
}